// Round 6
// baseline (314.561 us; speedup 1.0000x reference)
//
#include <hip/hip_runtime.h>

typedef short short8 __attribute__((ext_vector_type(8)));
typedef float f32x4 __attribute__((ext_vector_type(4)));

#define NV 131072
#define KK 27
#define CH 64
#define NP 8      // phases = ci chunks of 8 channels; chunk = NV*8*2B = 2.1 MB << 4MB L2
#define CE 8      // channels per chunk
#define NG 7      // tap-quads per phase (4*7=28, 28th tap is zero-pad)

#define FENCE asm volatile("" ::: "memory")

__device__ inline unsigned short f2b(float f) {
    unsigned u = __float_as_uint(f);
    u += 0x7fffu + ((u >> 16) & 1u);   // round-to-nearest-even
    return (unsigned short)(u >> 16);
}

// feat f32 [N][64] -> chunk-major bf16 xc8[8][N][8]
__global__ void prep_featc8(const float* __restrict__ feat, unsigned short* __restrict__ xc) {
    int tid = blockIdx.x * blockDim.x + threadIdx.x;   // N*16 threads
    int j = tid >> 4, u = tid & 15;
    float4 v = *reinterpret_cast<const float4*>(feat + j * CH + u * 4);
    int p = u >> 1, e0 = (u & 1) * 4;
    ushort4 o;
    o.x = f2b(v.x); o.y = f2b(v.y); o.z = f2b(v.z); o.w = f2b(v.w);
    *reinterpret_cast<ushort4*>(xc + ((size_t)p * NV + j) * CE + e0) = o;
}

// W [27][64][64] f32 -> wq [NP][NG][4tap][64o][8e] bf16 (tap 4g+t>=27 -> 0). Both layers.
__global__ void prep_wq(const float* __restrict__ W1, const float* __restrict__ W2,
                        unsigned short* __restrict__ wq1, unsigned short* __restrict__ wq2) {
    const int PER = NP * NG * 4 * 64 * CE;             // 114688
    int id = blockIdx.x * blockDim.x + threadIdx.x;    // 2*PER
    const float* W = W1; unsigned short* wq = wq1;
    int r = id;
    if (r >= PER) { r -= PER; W = W2; wq = wq2; }
    int e = r & 7, o = (r >> 3) & 63, t = (r >> 9) & 3, q = r >> 11;
    int g = q % NG, p = q / NG;
    int k = 4 * g + t, ci = p * CE + e;
    float v = (k < KK) ? W[(k * CH + ci) * CH + o] : 0.f;
    wq[r] = f2b(v);
}

__device__ inline void gld16(const void* gsrc, void* ldst) {
    __builtin_amdgcn_global_load_lds(
        (const __attribute__((address_space(1))) unsigned int*)gsrc,
        (__attribute__((address_space(3))) unsigned int*)ldst,
        16, 0, 0);
}

// 4 independent waves/block, wave owns 64 rows x 64 cols. 8 ci-phases x 7 tap-quad
// groups; each MFMA packs K=32 = 4 taps x 8 ch (no zero-pad waste). nbr lives in 27
// VGPRs for the whole kernel. Per-wave private 4-slot x 4KB LDS ring, staged 3 ahead,
// counted vmcnt (never drained in-loop).
template <int EPI>
__global__ __launch_bounds__(256, 2) void conv_q(
    const unsigned short* __restrict__ xc,    // [NP][NV][CE] chunk-major input
    const unsigned short* __restrict__ wq,    // [NP][NG][4][64][CE]
    const float* __restrict__ bias,           // [64]
    const int* __restrict__ nbr,              // [N][27]
    const float* __restrict__ resid,          // [N][64] f32 (EPI==1)
    unsigned short* __restrict__ hc,          // EPI0 out: [NP][NV][CE]
    float* __restrict__ outf)                 // EPI1 out: [N][64] f32
{
    __shared__ char ring[4][4][4096];         // [wave][slot][4 taps x 64 rows x 16B] = 64 KB
    const int tid  = threadIdx.x;
    const int wid  = tid >> 6;
    const int lane = tid & 63;
    const int lr   = lane & 15;
    const int kg   = lane >> 4;
    const int rowb = blockIdx.x * 256 + wid * 64;

    // all 27 neighbor indices of row (rowb+lane) -> VGPRs, once for the whole kernel
    int idx[KK];
    {
        const int* np_ = nbr + (size_t)(rowb + lane) * KK;
        #pragma unroll
        for (int k = 0; k < KK; ++k) idx[k] = np_[k];
    }
    asm volatile("s_waitcnt vmcnt(0)" ::: "memory");   // quiesce: per-phase counts exact

    f32x4 acc[4][4];
    #pragma unroll
    for (int rt = 0; rt < 4; ++rt)
        #pragma unroll
        for (int nt = 0; nt < 4; ++nt)
            acc[rt][nt] = (f32x4){0.f, 0.f, 0.f, 0.f};

    char* const ar = (char*)&ring[wid][0][0];
    short8 b[2][4];

    // stage group g of current phase into slot: 4 gld16, lane l covers row l of each tap
    auto stage = [&](int slot, int g, const unsigned short* xcc) {
        char* dst = ar + slot * 4096 + lane * 16;
        #pragma unroll
        for (int t = 0; t < 4; ++t) {
            int k = 4 * g + t; if (k > KK - 1) k = KK - 1;   // pad tap -> W is zero
            gld16(xcc + (size_t)idx[k] * CE, dst + t * 1024);
        }
    };
    auto loadB = [&](short8* d, const unsigned short* wg) {  // wg = group base (2048 elems)
        #pragma unroll
        for (int nt = 0; nt < 4; ++nt)
            d[nt] = *reinterpret_cast<const short8*>(wg + ((size_t)(kg * 64 + nt * 16 + lr)) * CE);
    };

    #pragma unroll 1
    for (int p = 0; p < NP; ++p) {
        const unsigned short* xcc = xc + (size_t)p * NV * CE;
        const unsigned short* wpp = wq + (size_t)p * NG * 2048;

        stage(0, 0, xcc); FENCE;
        stage(1, 1, xcc); FENCE;
        stage(2, 2, xcc); FENCE;
        loadB(b[0], wpp); FENCE;

        #pragma unroll
        for (int g = 0; g < NG; ++g) {
            // counted waits: stage(g) complete, newer loads stay in flight
            if      (g == 0) asm volatile("s_waitcnt vmcnt(12)" ::: "memory");
            else if (g == 1) asm volatile("s_waitcnt vmcnt(16)" ::: "memory");
            else if (g == 2) asm volatile("s_waitcnt vmcnt(20)" ::: "memory");
            else if (g == 3) asm volatile("s_waitcnt vmcnt(16)" ::: "memory");
            else if (g == 4) asm volatile("s_waitcnt vmcnt(16)" ::: "memory");
            else if (g == 5) asm volatile("s_waitcnt vmcnt(12)" ::: "memory");
            else             asm volatile("s_waitcnt vmcnt(8)"  ::: "memory");

            const char* ab = ar + (g & 3) * 4096;
            short8 a_[4];
            #pragma unroll
            for (int rt = 0; rt < 4; ++rt)
                a_[rt] = *reinterpret_cast<const short8*>(ab + kg * 1024 + (rt * 16 + lr) * 16);
            asm volatile("s_waitcnt lgkmcnt(0)" ::: "memory");
            __builtin_amdgcn_sched_barrier(0);

            if (g + 1 < NG) { loadB(b[(g + 1) & 1], wpp + (size_t)(g + 1) * 2048); }
            FENCE;
            if (g + 3 < NG) { stage((g + 3) & 3, g + 3, xcc); }
            FENCE;

            #pragma unroll
            for (int rt = 0; rt < 4; ++rt)
                #pragma unroll
                for (int nt = 0; nt < 4; ++nt)
                    acc[rt][nt] = __builtin_amdgcn_mfma_f32_16x16x32_bf16(
                        a_[rt], b[g & 1][nt], acc[rt][nt], 0, 0, 0);
        }
    }

    // Epilogue. D: col = nt*16+lr, row = rowb + rt*16 + kg*4 + i
    #pragma unroll
    for (int rt = 0; rt < 4; ++rt) {
        const int row0 = rowb + rt * 16 + kg * 4;
        #pragma unroll
        for (int nt = 0; nt < 4; ++nt) {
            int col = nt * 16 + lr;
            float bv = bias[col];
            #pragma unroll
            for (int i = 0; i < 4; ++i) {
                float v = acc[rt][nt][i] + bv;
                if (EPI == 0) {
                    v = fmaxf(v, 0.f);
                    hc[((size_t)(col >> 3) * NV + (row0 + i)) * CE + (col & 7)] = f2b(v);
                } else {
                    v += __builtin_nontemporal_load(resid + (size_t)(row0 + i) * CH + col);
                    v = fmaxf(v, 0.f);
                    __builtin_nontemporal_store(v, outf + (size_t)(row0 + i) * CH + col);
                }
            }
        }
    }
}

extern "C" void kernel_launch(void* const* d_in, const int* in_sizes, int n_in,
                              void* d_out, int out_size, void* d_ws, size_t ws_size,
                              hipStream_t stream) {
    const float* feat = (const float*)d_in[0];
    const float* W1   = (const float*)d_in[1];
    const float* b1   = (const float*)d_in[2];
    const float* W2   = (const float*)d_in[3];
    const float* b2   = (const float*)d_in[4];
    const int*   nbr  = (const int*)d_in[5];
    float* out = (float*)d_out;

    const int PER = NP * NG * 4 * 64 * CE;                                     // 114688
    char* ws = (char*)d_ws;
    unsigned short* xc8 = (unsigned short*)ws;                                 // 16.78 MB
    unsigned short* hcb = (unsigned short*)(ws + (size_t)NV * CH * 2);         // 16.78 MB
    unsigned short* wq1 = (unsigned short*)(ws + (size_t)NV * CH * 4);         // 229 KB
    unsigned short* wq2 = wq1 + PER;                                           // 229 KB

    prep_featc8<<<NV * 16 / 256, 256, 0, stream>>>(feat, xc8);
    prep_wq<<<2 * PER / 256, 256, 0, stream>>>(W1, W2, wq1, wq2);
    conv_q<0><<<NV / 256, 256, 0, stream>>>(xc8, wq1, b1, nbr, nullptr, hcb, nullptr);
    conv_q<1><<<NV / 256, 256, 0, stream>>>(hcb, wq2, b2, nbr, feat, nullptr, out);
}

// Round 7
// 299.381 us; speedup vs baseline: 1.0507x; 1.0507x over previous
//
#include <hip/hip_runtime.h>

typedef short short8 __attribute__((ext_vector_type(8)));
typedef float f32x4 __attribute__((ext_vector_type(4)));

#define NV 131072
#define KK 27
#define CH 64
#define NP 4      // phases = ci chunks of 16 channels; chunk = NV*16*2B = 4.2 MB ~ L2
#define CE 16     // channels per chunk
#define NG 14     // tap-pairs per phase (2*14=28, tap 27 is zero-pad)

#define FENCE asm volatile("" ::: "memory")

__device__ inline unsigned short f2b(float f) {
    unsigned u = __float_as_uint(f);
    u += 0x7fffu + ((u >> 16) & 1u);   // round-to-nearest-even
    return (unsigned short)(u >> 16);
}

// feat f32 [N][64] -> chunk-major bf16 xc[4][N][16]
__global__ void prep_featc(const float* __restrict__ feat, unsigned short* __restrict__ xc) {
    int tid = blockIdx.x * blockDim.x + threadIdx.x;   // N*16 threads
    int j = tid >> 4, u = tid & 15;
    float4 v = *reinterpret_cast<const float4*>(feat + j * CH + u * 4);
    int p = u >> 2, e0 = (u & 3) * 4;
    ushort4 o;
    o.x = f2b(v.x); o.y = f2b(v.y); o.z = f2b(v.z); o.w = f2b(v.w);
    *reinterpret_cast<ushort4*>(xc + ((size_t)p * NV + j) * CE + e0) = o;
}

// W [27][64][64] f32 -> wq [NP][NG][64 o][32 kk] bf16; kk = tl*16+ce, k=2g+tl (>=27 -> 0)
__global__ void prep_wq(const float* __restrict__ W1, const float* __restrict__ W2,
                        unsigned short* __restrict__ wq1, unsigned short* __restrict__ wq2) {
    const int PER = NP * NG * 64 * 32;                 // 114688
    int id = blockIdx.x * blockDim.x + threadIdx.x;    // 2*PER
    const float* W = W1; unsigned short* wq = wq1;
    int r = id;
    if (r >= PER) { r -= PER; W = W2; wq = wq2; }
    int kk = r & 31, o = (r >> 5) & 63, q = r >> 11;
    int g = q % NG, p = q / NG;
    int tl = kk >> 4, ce = kk & 15;
    int k = 2 * g + tl, ci = p * CE + ce;
    float v = (k < KK) ? W[(k * CH + ci) * CH + o] : 0.f;
    wq[r] = f2b(v);
}

__device__ inline void gld16(const void* gsrc, void* ldst) {
    __builtin_amdgcn_global_load_lds(
        (const __attribute__((address_space(1))) unsigned int*)gsrc,
        (__attribute__((address_space(3))) unsigned int*)ldst,
        16, 0, 0);
}

// 4 independent waves/block, wave owns 64 rows x 64 cols. 4 ci-phases x 14 tap-pair
// groups; each MFMA packs K=32 = 2 taps x 16 ch (no zero-pad waste). idx in 27 VGPRs.
// Per-wave private 3-slot x 4KB LDS ring, staged 2 ahead; loadB issued BEFORE stage so
// the compiler's b-register wait keeps the stage queue in flight (no drain).
// Slot layout: [tap 2][half 2][row 64][16B]; lane l stages row l (its own idx).
template <int EPI>
__global__ __launch_bounds__(256, 2) void conv_q2(
    const unsigned short* __restrict__ xc,    // [NP][NV][CE] chunk-major input
    const unsigned short* __restrict__ wq,    // [NP][NG][64][32]
    const float* __restrict__ bias,           // [64]
    const int* __restrict__ nbr,              // [N][27]
    const float* __restrict__ resid,          // [N][64] f32 (EPI==1)
    unsigned short* __restrict__ hc,          // EPI0 out: [NP][NV][CE]
    float* __restrict__ outf)                 // EPI1 out: [N][64] f32
{
    __shared__ char ring[4][3][4096];         // [wave][slot][2tap x 2half x 64row x 16B] = 48 KB
    const int tid  = threadIdx.x;
    const int wid  = tid >> 6;
    const int lane = tid & 63;
    const int lr   = lane & 15;
    const int kg   = lane >> 4;
    const int rowb = blockIdx.x * 256 + wid * 64;

    // all 27 neighbor indices of row (rowb+lane) -> VGPRs, once for the whole kernel
    int idx[KK];
    {
        const int* np_ = nbr + (size_t)(rowb + lane) * KK;
        #pragma unroll
        for (int k = 0; k < KK; ++k) idx[k] = np_[k];
    }
    asm volatile("s_waitcnt vmcnt(0)" ::: "memory");   // quiesce: per-phase counts exact

    f32x4 acc[4][4];
    #pragma unroll
    for (int rt = 0; rt < 4; ++rt)
        #pragma unroll
        for (int nt = 0; nt < 4; ++nt)
            acc[rt][nt] = (f32x4){0.f, 0.f, 0.f, 0.f};

    char* const ar = (char*)&ring[wid][0][0];
    short8 b[2][4];

    // stage group g: taps 2g, 2g+1 (clamped; pad tap's W is zero), 4 gld16.
    // lane l loads row l, half h: 16 B at xcc + idx*32B + h*16B -> dst + l*16.
    auto stage = [&](int slot, int g, const unsigned short* xcc) {
        char* dst = ar + slot * 4096;
        #pragma unroll
        for (int t = 0; t < 2; ++t) {
            int k = 2 * g + t; if (k > KK - 1) k = KK - 1;
            const unsigned short* src = xcc + (size_t)idx[k] * CE;
            gld16(src,     dst + t * 2048);
            gld16(src + 8, dst + t * 2048 + 1024);
        }
    };
    auto loadB = [&](short8* d, const unsigned short* wg) {  // wg = group base (2048 elems)
        #pragma unroll
        for (int nt = 0; nt < 4; ++nt)
            d[nt] = *reinterpret_cast<const short8*>(wg + (size_t)(nt * 16 + lr) * 32 + kg * 8);
    };

    #pragma unroll 1
    for (int p = 0; p < NP; ++p) {
        const unsigned short* xcc = xc + (size_t)p * NV * CE;
        const unsigned short* wpp = wq + (size_t)p * NG * 2048;

        stage(0, 0, xcc); FENCE;
        stage(1, 1, xcc); FENCE;
        loadB(b[0], wpp); FENCE;

        #pragma unroll
        for (int g = 0; g < NG; ++g) {
            // counted wait: stage(g) complete; newer [B(g)][s(g+1)] stay in flight
            if (g < NG - 1) asm volatile("s_waitcnt vmcnt(8)" ::: "memory");
            else            asm volatile("s_waitcnt vmcnt(4)" ::: "memory");

            const char* ab = ar + (g % 3) * 4096;
            short8 a_[4];
            #pragma unroll
            for (int rt = 0; rt < 4; ++rt)
                a_[rt] = *reinterpret_cast<const short8*>(
                    ab + (kg >> 1) * 2048 + (kg & 1) * 1024 + (rt * 16 + lr) * 16);
            asm volatile("s_waitcnt lgkmcnt(0)" ::: "memory");
            __builtin_amdgcn_sched_barrier(0);

            if (g + 1 < NG) { loadB(b[(g + 1) & 1], wpp + (size_t)(g + 1) * 2048); }
            FENCE;
            if (g + 2 < NG) { stage((g + 2) % 3, g + 2, xcc); }
            FENCE;

            #pragma unroll
            for (int rt = 0; rt < 4; ++rt)
                #pragma unroll
                for (int nt = 0; nt < 4; ++nt)
                    acc[rt][nt] = __builtin_amdgcn_mfma_f32_16x16x32_bf16(
                        a_[rt], b[g & 1][nt], acc[rt][nt], 0, 0, 0);
        }
    }

    // Epilogue. D: col = nt*16+lr, row = rowb + rt*16 + kg*4 + i
    #pragma unroll
    for (int rt = 0; rt < 4; ++rt) {
        const int row0 = rowb + rt * 16 + kg * 4;
        #pragma unroll
        for (int nt = 0; nt < 4; ++nt) {
            int col = nt * 16 + lr;
            float bv = bias[col];
            #pragma unroll
            for (int i = 0; i < 4; ++i) {
                float v = acc[rt][nt][i] + bv;
                if (EPI == 0) {
                    v = fmaxf(v, 0.f);
                    hc[((size_t)(col >> 4) * NV + (row0 + i)) * CE + (col & 15)] = f2b(v);
                } else {
                    v += __builtin_nontemporal_load(resid + (size_t)(row0 + i) * CH + col);
                    v = fmaxf(v, 0.f);
                    __builtin_nontemporal_store(v, outf + (size_t)(row0 + i) * CH + col);
                }
            }
        }
    }
}

extern "C" void kernel_launch(void* const* d_in, const int* in_sizes, int n_in,
                              void* d_out, int out_size, void* d_ws, size_t ws_size,
                              hipStream_t stream) {
    const float* feat = (const float*)d_in[0];
    const float* W1   = (const float*)d_in[1];
    const float* b1   = (const float*)d_in[2];
    const float* W2   = (const float*)d_in[3];
    const float* b2   = (const float*)d_in[4];
    const int*   nbr  = (const int*)d_in[5];
    float* out = (float*)d_out;

    const int PER = NP * NG * 64 * 32;                                         // 114688
    char* ws = (char*)d_ws;
    unsigned short* xcb = (unsigned short*)ws;                                 // 16.78 MB
    unsigned short* hcb = (unsigned short*)(ws + (size_t)NV * CH * 2);         // 16.78 MB
    unsigned short* wq1 = (unsigned short*)(ws + (size_t)NV * CH * 4);         // 229 KB
    unsigned short* wq2 = wq1 + PER;                                           // 229 KB

    prep_featc<<<NV * 16 / 256, 256, 0, stream>>>(feat, xcb);
    prep_wq<<<2 * PER / 256, 256, 0, stream>>>(W1, W2, wq1, wq2);
    conv_q2<0><<<NV / 256, 256, 0, stream>>>(xcb, wq1, b1, nbr, nullptr, hcb, nullptr);
    conv_q2<1><<<NV / 256, 256, 0, stream>>>(hcb, wq2, b2, nbr, feat, nullptr, out);
}

// Round 8
// 246.693 us; speedup vs baseline: 1.2751x; 1.2136x over previous
//
#include <hip/hip_runtime.h>

typedef short short8 __attribute__((ext_vector_type(8)));
typedef float f32x4 __attribute__((ext_vector_type(4)));

#define NV 131072
#define KK 27
#define CH 64
#define NP 4      // ci phases; chunk = NV*CE*2B = 4.2 MB ~ one XCD L2
#define CE 16     // channels per chunk
#define NG2 14    // tap-pair groups per phase (2*14=28, tap 27 -> zero weights)

#define FENCE asm volatile("" ::: "memory")

__device__ inline unsigned short f2b(float f) {
    unsigned u = __float_as_uint(f);
    u += 0x7fffu + ((u >> 16) & 1u);   // round-to-nearest-even
    return (unsigned short)(u >> 16);
}

// feat f32 [N][64] -> chunk-major bf16 xc[4][N][16]
__global__ void prep_featc(const float* __restrict__ feat, unsigned short* __restrict__ xc) {
    int tid = blockIdx.x * blockDim.x + threadIdx.x;   // N*16 threads
    int j = tid >> 4, u = tid & 15;
    float4 v = *reinterpret_cast<const float4*>(feat + j * CH + u * 4);
    int p = u >> 2, e0 = (u & 3) * 4;
    ushort4 o;
    o.x = f2b(v.x); o.y = f2b(v.y); o.z = f2b(v.z); o.w = f2b(v.w);
    *reinterpret_cast<ushort4*>(xc + ((size_t)p * NV + j) * CE + e0) = o;
}

// W [27][64][64] f32 -> wq [NP][NG2][64 o][32 kk]; kk = tl*16+ce, tap k=2g+tl (k>=27 -> 0)
__global__ void prep_wq(const float* __restrict__ W1, const float* __restrict__ W2,
                        unsigned short* __restrict__ wq1, unsigned short* __restrict__ wq2) {
    const int PER = NP * NG2 * 64 * 32;                // 114688
    int id = blockIdx.x * blockDim.x + threadIdx.x;    // 2*PER
    const float* W = W1; unsigned short* wq = wq1;
    int r = id;
    if (r >= PER) { r -= PER; W = W2; wq = wq2; }
    int kk = r & 31, o = (r >> 5) & 63, q = r >> 11;
    int g = q % NG2, p = q / NG2;
    int tl = kk >> 4, ce = kk & 15;
    int k = 2 * g + tl, ci = p * CE + ce;
    float v = (k < KK) ? W[(k * CH + ci) * CH + o] : 0.f;
    wq[r] = f2b(v);
}

__device__ inline void gld16(const void* gsrc, void* ldst) {
    __builtin_amdgcn_global_load_lds(
        (const __attribute__((address_space(1))) unsigned int*)gsrc,
        (__attribute__((address_space(3))) unsigned int*)ldst,
        16, 0, 0);
}

// 4 independent waves/block; wave owns 64 rows x 64 cols. 4 ci-phases x 14 tap-pair
// groups; MFMA K=32 = 2 taps x 16 ch. A-staging identical to R5 (paired lanes: 32B
// coalesced requests; idx from LDS). Per-wave ring: 3 slot-PAIRS x 4KB. B triple-
// buffered, loaded 2 groups ahead. Uniform counted schedule: queue per group =
// [sg(g) B(g) sg(g+1) B(g+1) sg(g+2)] -> steady wait vmcnt(12), never drained.
template <int EPI>
__global__ __launch_bounds__(256, 2) void conv_p2(
    const unsigned short* __restrict__ xc,    // [NP][NV][CE]
    const unsigned short* __restrict__ wq,    // [NP][NG2][64][32]
    const float* __restrict__ bias,           // [64]
    const int* __restrict__ nbr,              // [N][27]
    const float* __restrict__ resid,          // [N][64] f32 (EPI==1)
    unsigned short* __restrict__ hc,          // EPI0 out: [NP][NV][CE]
    float* __restrict__ outf)                 // EPI1 out: [N][64] f32
{
    __shared__ int  idxl[256 * KK];           // 27648 B (block rows, row-major [256][27])
    __shared__ char ring[4][3][4096];         // 49152 B: [wave][pair][2 taps x 64 rows x 32B]
    const int tid  = threadIdx.x;
    const int wid  = tid >> 6;
    const int lane = tid & 63;
    const int lr   = lane & 15;
    const int kg   = lane >> 4;
    const int rowb = blockIdx.x * 256 + wid * 64;

    #pragma unroll
    for (int e = 0; e < KK; ++e)
        idxl[e * 256 + tid] = nbr[(size_t)blockIdx.x * 256 * KK + e * 256 + tid];
    __syncthreads();

    const int* myidx = idxl + wid * 64 * KK;  // this wave's [64][27]
    char* const ar = (char*)&ring[wid][0][0];

    f32x4 acc[4][4];
    #pragma unroll
    for (int rt = 0; rt < 4; ++rt)
        #pragma unroll
        for (int nt = 0; nt < 4; ++nt)
            acc[rt][nt] = (f32x4){0.f, 0.f, 0.f, 0.f};

    short8 b[3][4];

    // B for group g: lane (lr,kg) takes kk = kg*8..kg*8+7 of cols nt*16+lr
    auto loadB = [&](short8* d, const unsigned short* wg) {
        #pragma unroll
        for (int nt = 0; nt < 4; ++nt)
            d[nt] = *reinterpret_cast<const short8*>(wg + (size_t)(nt * 16 + lr) * 32 + kg * 8);
    };
    // stage group g into pair g%3: per tap 2 gld16, paired lanes (row = lane>>1, half = lane&1)
    auto stage2 = [&](int g, const unsigned short* xcc, int v00, int v01, int v10, int v11) {
        char* dst = ar + (g % 3) * 4096;
        gld16(xcc + (size_t)v00 * CE + (lane & 1) * 8, dst);
        gld16(xcc + (size_t)v01 * CE + (lane & 1) * 8, dst + 1024);
        gld16(xcc + (size_t)v10 * CE + (lane & 1) * 8, dst + 2048);
        gld16(xcc + (size_t)v11 * CE + (lane & 1) * 8, dst + 3072);
    };

    #pragma unroll 1
    for (int p = 0; p < NP; ++p) {
        const unsigned short* xcc = xc + (size_t)p * NV * CE;
        const unsigned short* wpp = wq + (size_t)p * NG2 * 2048;

        // prologue: idx for groups 0..2, then queue = sg0 B0 sg1 B1 sg2 (20 VMEM)
        int pv[3][4];
        #pragma unroll
        for (int g = 0; g < 3; ++g) {
            int k0 = 2 * g, k1 = 2 * g + 1;
            pv[g][0] = myidx[(lane >> 1) * KK + k0];
            pv[g][1] = myidx[(32 + (lane >> 1)) * KK + k0];
            pv[g][2] = myidx[(lane >> 1) * KK + k1];
            pv[g][3] = myidx[(32 + (lane >> 1)) * KK + k1];
        }
        asm volatile("s_waitcnt lgkmcnt(0)" ::: "memory");
        stage2(0, xcc, pv[0][0], pv[0][1], pv[0][2], pv[0][3]); FENCE;
        loadB(b[0], wpp);                                       FENCE;
        stage2(1, xcc, pv[1][0], pv[1][1], pv[1][2], pv[1][3]); FENCE;
        loadB(b[1], wpp + 2048);                                FENCE;
        stage2(2, xcc, pv[2][0], pv[2][1], pv[2][2], pv[2][3]); FENCE;

        #pragma unroll
        for (int g = 0; g < NG2; ++g) {
            // steady: [sg(g) B(g) sg(g+1) B(g+1) sg(g+2)] outstanding -> complete sg(g),B(g)
            if      (g < 12)  asm volatile("s_waitcnt vmcnt(12)" ::: "memory");
            else if (g == 12) asm volatile("s_waitcnt vmcnt(8)"  ::: "memory");
            else              asm volatile("s_waitcnt vmcnt(0)"  ::: "memory");

            const char* pbase = ar + (g % 3) * 4096 + (kg >> 1) * 2048;
            short8 a_[4];
            #pragma unroll
            for (int rt = 0; rt < 4; ++rt)
                a_[rt] = *reinterpret_cast<const short8*>(pbase + (rt * 16 + lr) * 32 + (kg & 1) * 16);

            int v00 = 0, v01 = 0, v10 = 0, v11 = 0;
            if (g + 3 < NG2) {
                int k0 = 2 * (g + 3), k1 = 2 * (g + 3) + 1; if (k1 > KK - 1) k1 = KK - 1;
                v00 = myidx[(lane >> 1) * KK + k0];
                v01 = myidx[(32 + (lane >> 1)) * KK + k0];
                v10 = myidx[(lane >> 1) * KK + k1];
                v11 = myidx[(32 + (lane >> 1)) * KK + k1];
            }
            asm volatile("s_waitcnt lgkmcnt(0)" ::: "memory");
            __builtin_amdgcn_sched_barrier(0);

            if (g + 2 < NG2) { loadB(b[(g + 2) % 3], wpp + (size_t)(g + 2) * 2048); }
            FENCE;
            if (g + 3 < NG2) { stage2(g + 3, xcc, v00, v01, v10, v11); }
            FENCE;

            #pragma unroll
            for (int rt = 0; rt < 4; ++rt)
                #pragma unroll
                for (int nt = 0; nt < 4; ++nt)
                    acc[rt][nt] = __builtin_amdgcn_mfma_f32_16x16x32_bf16(
                        a_[rt], b[g % 3][nt], acc[rt][nt], 0, 0, 0);
        }
    }

    // Epilogue. D: col = nt*16+lr, row = rowb + rt*16 + kg*4 + i
    #pragma unroll
    for (int rt = 0; rt < 4; ++rt) {
        const int row0 = rowb + rt * 16 + kg * 4;
        #pragma unroll
        for (int nt = 0; nt < 4; ++nt) {
            int col = nt * 16 + lr;
            float bv = bias[col];
            #pragma unroll
            for (int i = 0; i < 4; ++i) {
                float v = acc[rt][nt][i] + bv;
                if (EPI == 0) {
                    v = fmaxf(v, 0.f);
                    hc[((size_t)nt * NV + (row0 + i)) * CE + lr] = f2b(v);
                } else {
                    v += __builtin_nontemporal_load(resid + (size_t)(row0 + i) * CH + col);
                    v = fmaxf(v, 0.f);
                    __builtin_nontemporal_store(v, outf + (size_t)(row0 + i) * CH + col);
                }
            }
        }
    }
}

extern "C" void kernel_launch(void* const* d_in, const int* in_sizes, int n_in,
                              void* d_out, int out_size, void* d_ws, size_t ws_size,
                              hipStream_t stream) {
    const float* feat = (const float*)d_in[0];
    const float* W1   = (const float*)d_in[1];
    const float* b1   = (const float*)d_in[2];
    const float* W2   = (const float*)d_in[3];
    const float* b2   = (const float*)d_in[4];
    const int*   nbr  = (const int*)d_in[5];
    float* out = (float*)d_out;

    const int PER = NP * NG2 * 64 * 32;                                        // 114688
    char* ws = (char*)d_ws;
    unsigned short* xcb = (unsigned short*)ws;                                 // 16.78 MB
    unsigned short* hcb = (unsigned short*)(ws + (size_t)NV * CH * 2);         // 16.78 MB
    unsigned short* wq1 = (unsigned short*)(ws + (size_t)NV * CH * 4);         // 229 KB
    unsigned short* wq2 = wq1 + PER;                                           // 229 KB

    prep_featc<<<NV * 16 / 256, 256, 0, stream>>>(feat, xcb);
    prep_wq<<<2 * PER / 256, 256, 0, stream>>>(W1, W2, wq1, wq2);
    conv_p2<0><<<NV / 256, 256, 0, stream>>>(xcb, wq1, b1, nbr, nullptr, hcb, nullptr);
    conv_p2<1><<<NV / 256, 256, 0, stream>>>(hcb, wq2, b2, nbr, feat, nullptr, out);
}

// Round 9
// 180.101 us; speedup vs baseline: 1.7466x; 1.3698x over previous
//
#include <hip/hip_runtime.h>

typedef short short8 __attribute__((ext_vector_type(8)));
typedef float f32x4 __attribute__((ext_vector_type(4)));

#define NV 131072
#define KK 27
#define CH 64
#define NP 4      // ci phases; chunk = NV*CE*2B = 4.2 MB ~ one XCD L2
#define CE 16     // channels per chunk
#define NG2 14    // tap-pair groups per phase (2*14=28, tap 27 -> zero weights)

#define FENCE asm volatile("" ::: "memory")

__device__ inline unsigned short f2b(float f) {
    unsigned u = __float_as_uint(f);
    u += 0x7fffu + ((u >> 16) & 1u);   // round-to-nearest-even
    return (unsigned short)(u >> 16);
}

// feat f32 [N][64] -> chunk-major bf16 xc[4][N][16]
__global__ void prep_featc(const float* __restrict__ feat, unsigned short* __restrict__ xc) {
    int tid = blockIdx.x * blockDim.x + threadIdx.x;   // N*16 threads
    int j = tid >> 4, u = tid & 15;
    float4 v = *reinterpret_cast<const float4*>(feat + j * CH + u * 4);
    int p = u >> 2, e0 = (u & 3) * 4;
    ushort4 o;
    o.x = f2b(v.x); o.y = f2b(v.y); o.z = f2b(v.z); o.w = f2b(v.w);
    *reinterpret_cast<ushort4*>(xc + ((size_t)p * NV + j) * CE + e0) = o;
}

// W [27][64][64] f32 -> wq [NP][NG2][nt 4][lane 64][8e] bf16, exactly the per-lane
// ds_read order. lane=(kg,lr): col=nt*16+lr, kk=kg*8+e, tap=2g+(kk>>4), ci=p*16+(kk&15).
__global__ void prep_wq(const float* __restrict__ W1, const float* __restrict__ W2,
                        unsigned short* __restrict__ wq1, unsigned short* __restrict__ wq2) {
    const int PER = NP * NG2 * 4 * 64 * 8;             // 114688
    int id = blockIdx.x * blockDim.x + threadIdx.x;    // 2*PER
    const float* W = W1; unsigned short* wq = wq1;
    int r = id;
    if (r >= PER) { r -= PER; W = W2; wq = wq2; }
    int e = r & 7, lane = (r >> 3) & 63, nt = (r >> 9) & 3, q = r >> 11;
    int g = q % NG2, p = q / NG2;
    int col = nt * 16 + (lane & 15);
    int kk  = (lane >> 4) * 8 + e;
    int k   = 2 * g + (kk >> 4);
    int ci  = p * CE + (kk & 15);
    float v = (k < KK) ? W[(k * CH + ci) * CH + col] : 0.f;
    wq[r] = f2b(v);
}

__device__ inline void gld16(const void* gsrc, void* ldst) {
    __builtin_amdgcn_global_load_lds(
        (const __attribute__((address_space(1))) unsigned int*)gsrc,
        (__attribute__((address_space(3))) unsigned int*)ldst,
        16, 0, 0);
}

// Block = 512 thr = 8 waves, wave owns 64 rows x 64 cols; grid = N/512 = 256 -> fully
// resident at 1 block/CU. 4 ci-phases x 14 tap-pair groups (MFMA K=32 = 2 taps x 16ch).
// Steady-loop VMEM queue = ONLY A-stages (4 x 32B-coalesced gld16 per group): B lives in
// LDS (staged once/phase/block, lane-packed -> linear conflict-free ds_read_b128), idx
// lives in VGPRs (27/lane, one coalesced load, shfl to paired lanes). Uniform vmcnt(8).
template <int EPI>
__global__ __launch_bounds__(512, 1) void conv_bl(
    const unsigned short* __restrict__ xc,    // [NP][NV][CE]
    const unsigned short* __restrict__ wq,    // [NP][NG2][4][64][8]
    const float* __restrict__ bias,           // [64]
    const int* __restrict__ nbr,              // [N][27]
    const float* __restrict__ resid,          // [N][64] f32 (EPI==1)
    unsigned short* __restrict__ hc,          // EPI0 out: [NP][NV][CE]
    float* __restrict__ outf)                 // EPI1 out: [N][64] f32
{
    __shared__ char ringA[8][3][4096];        // 96 KB: [wave][pair-slot][2tap x 64row x 32B]
    __shared__ char ldsB[NG2 * 4096];         // 56 KB: [group][nt][lane][16B]
    const int tid  = threadIdx.x;
    const int wid  = tid >> 6;
    const int lane = tid & 63;
    const int lr   = lane & 15;
    const int kg   = lane >> 4;
    const int rowb = blockIdx.x * 512 + wid * 64;

    // per-lane: all 27 neighbor indices of row (rowb+lane); wave load is 64x108B contiguous
    int idx[KK];
    {
        const int* np_ = nbr + (size_t)(rowb + lane) * KK;
        #pragma unroll
        for (int k = 0; k < KK; ++k) idx[k] = np_[k];
    }

    f32x4 acc[4][4];
    #pragma unroll
    for (int rt = 0; rt < 4; ++rt)
        #pragma unroll
        for (int nt = 0; nt < 4; ++nt)
            acc[rt][nt] = (f32x4){0.f, 0.f, 0.f, 0.f};

    char* const myring = (char*)&ringA[wid][0][0];

    // stage pair-group g (taps 2g, 2g+1): 4 gld16, paired lanes -> 32B coalesced requests.
    // slot layout [tap][row][32B]; lane l covers row l>>1 (+32), half (l&1).
    auto stageg = [&](int g, const unsigned short* xcc) {
        char* dst = myring + (g % 3) * 4096;
        const int k0 = 2 * g, k1 = (2 * g + 1 < KK) ? 2 * g + 1 : KK - 1;  // pad tap: W==0
        int r = lane >> 1, h = (lane & 1) * 8;
        int v00 = __shfl(idx[k0], r), v01 = __shfl(idx[k0], 32 + r);
        int v10 = __shfl(idx[k1], r), v11 = __shfl(idx[k1], 32 + r);
        gld16(xcc + (size_t)v00 * CE + h, dst);
        gld16(xcc + (size_t)v01 * CE + h, dst + 1024);
        gld16(xcc + (size_t)v10 * CE + h, dst + 2048);
        gld16(xcc + (size_t)v11 * CE + h, dst + 3072);
    };

    #pragma unroll 1
    for (int p = 0; p < NP; ++p) {
        const unsigned short* xcc = xc + (size_t)p * NV * CE;
        const char* wqp = (const char*)wq + (size_t)p * NG2 * 4096;

        if (p) __syncthreads();               // all waves done reading old B
        // B for the whole phase: 7 contiguous gld16 per thread (56 KB / block)
        #pragma unroll
        for (int i = 0; i < 7; ++i) {
            int off = (i * 8 + wid) * 1024;
            gld16(wqp + off + lane * 16, ldsB + off);
        }
        FENCE;
        stageg(0, xcc); FENCE;
        stageg(1, xcc); FENCE;
        stageg(2, xcc); FENCE;
        asm volatile("s_waitcnt vmcnt(8)" ::: "memory");   // B + A(0) done; A(1),A(2) in flight
        __syncthreads();                       // everyone's B slice landed

        #pragma unroll
        for (int g = 0; g < NG2; ++g) {
            if      (g < NG2 - 2) asm volatile("s_waitcnt vmcnt(8)" ::: "memory");
            else if (g == NG2-2)  asm volatile("s_waitcnt vmcnt(4)" ::: "memory");
            else                  asm volatile("s_waitcnt vmcnt(0)" ::: "memory");

            const char* ab = myring + (g % 3) * 4096 + (kg >> 1) * 2048;
            short8 a_[4];
            #pragma unroll
            for (int rt = 0; rt < 4; ++rt)
                a_[rt] = *reinterpret_cast<const short8*>(ab + (rt * 16 + lr) * 32 + (kg & 1) * 16);
            short8 b_[4];
            #pragma unroll
            for (int nt = 0; nt < 4; ++nt)
                b_[nt] = *reinterpret_cast<const short8*>(ldsB + g * 4096 + nt * 1024 + lane * 16);
            asm volatile("s_waitcnt lgkmcnt(0)" ::: "memory");
            __builtin_amdgcn_sched_barrier(0);

            if (g + 3 < NG2) { stageg(g + 3, xcc); }
            FENCE;

            #pragma unroll
            for (int rt = 0; rt < 4; ++rt)
                #pragma unroll
                for (int nt = 0; nt < 4; ++nt)
                    acc[rt][nt] = __builtin_amdgcn_mfma_f32_16x16x32_bf16(
                        a_[rt], b_[nt], acc[rt][nt], 0, 0, 0);
        }
    }

    // Epilogue. D: col = nt*16+lr, row = rowb + rt*16 + kg*4 + i
    #pragma unroll
    for (int rt = 0; rt < 4; ++rt) {
        const int row0 = rowb + rt * 16 + kg * 4;
        #pragma unroll
        for (int nt = 0; nt < 4; ++nt) {
            int col = nt * 16 + lr;
            float bv = bias[col];
            #pragma unroll
            for (int i = 0; i < 4; ++i) {
                float v = acc[rt][nt][i] + bv;
                if (EPI == 0) {
                    v = fmaxf(v, 0.f);
                    hc[((size_t)nt * NV + (row0 + i)) * CE + lr] = f2b(v);
                } else {
                    v += __builtin_nontemporal_load(resid + (size_t)(row0 + i) * CH + col);
                    v = fmaxf(v, 0.f);
                    __builtin_nontemporal_store(v, outf + (size_t)(row0 + i) * CH + col);
                }
            }
        }
    }
}

extern "C" void kernel_launch(void* const* d_in, const int* in_sizes, int n_in,
                              void* d_out, int out_size, void* d_ws, size_t ws_size,
                              hipStream_t stream) {
    const float* feat = (const float*)d_in[0];
    const float* W1   = (const float*)d_in[1];
    const float* b1   = (const float*)d_in[2];
    const float* W2   = (const float*)d_in[3];
    const float* b2   = (const float*)d_in[4];
    const int*   nbr  = (const int*)d_in[5];
    float* out = (float*)d_out;

    const int PER = NP * NG2 * 4 * 64 * 8;                                     // 114688
    char* ws = (char*)d_ws;
    unsigned short* xcb = (unsigned short*)ws;                                 // 16.78 MB
    unsigned short* hcb = (unsigned short*)(ws + (size_t)NV * CH * 2);         // 16.78 MB
    unsigned short* wq1 = (unsigned short*)(ws + (size_t)NV * CH * 4);         // 229 KB
    unsigned short* wq2 = wq1 + PER;                                           // 229 KB

    prep_featc<<<NV * 16 / 256, 256, 0, stream>>>(feat, xcb);
    prep_wq<<<2 * PER / 256, 256, 0, stream>>>(W1, W2, wq1, wq2);
    conv_bl<0><<<NV / 512, 512, 0, stream>>>(xcb, wq1, b1, nbr, nullptr, hcb, nullptr);
    conv_bl<1><<<NV / 512, 512, 0, stream>>>(hcb, wq2, b2, nbr, feat, nullptr, out);
}